// Round 4
// baseline (150.583 us; speedup 1.0000x reference)
//
#include <hip/hip_runtime.h>

#define C_IN   1024
#define C4     (C_IN / 4)      // 256 float4 per row (also C_out/4)
#define KCNT   256
#define TAU    0.05f           // split-bf16 score error ~1e-3 -> 50x margin

#define MB     32              // rows per block -> grid 512 = 2 blocks/CU
#define KC     64              // k-chunk staged in LDS (64 KB hi+lo)
#define NCHUNK (C_IN / KC)     // 16

typedef __attribute__((ext_vector_type(8)))  short bf16x8;
typedef __attribute__((ext_vector_type(16))) float f32x16;

static __device__ __forceinline__ unsigned short f2bf(float f) {
    union { float f; unsigned u; } v; v.f = f;
    unsigned r = v.u + 0x7fffu + ((v.u >> 16) & 1u);   // RNE
    return (unsigned short)(r >> 16);
}
static __device__ __forceinline__ float bf2f(unsigned short h) {
    union { unsigned u; float f; } v; v.u = (unsigned)h << 16;
    return v.f;
}
static __device__ __forceinline__ void load_lds16(const void* g, void* l) {
    __builtin_amdgcn_global_load_lds(
        (const __attribute__((address_space(1))) unsigned int*)g,
        (__attribute__((address_space(3))) unsigned int*)l, 16, 0, 0);
}

// ---------------------------------------------------------------------------
// Prep (validated round 3): keys -> hi/lo bf16 pre-swizzled linear LDS image:
// per-chunk 32 KB region: byte = key*128 + ((kk*2) ^ ((key&7)<<4)).
// Also k2[key] = ||key||^2 fp32.
// ---------------------------------------------------------------------------
__global__ __launch_bounds__(256) void prep_mfma(const float* __restrict__ keys,
        unsigned short* __restrict__ kws_hi, unsigned short* __restrict__ kws_lo,
        float* __restrict__ k2) {
    const int key = blockIdx.x, t = threadIdx.x;
    float4 v = ((const float4*)keys)[(size_t)key * C4 + t];
    float f[4] = {v.x, v.y, v.z, v.w};
    short h[4], lo[4];
#pragma unroll
    for (int i = 0; i < 4; ++i) {
        unsigned short hh = f2bf(f[i]);
        h[i] = (short)hh;
        lo[i] = (short)f2bf(f[i] - bf2f(hh));   // exact residual
    }
    const int c = t * 4, chunk = c >> 6, kk = c & 63;
    const size_t boff = (size_t)chunk * 32768 + (size_t)key * 128
                      + (size_t)((kk * 2) ^ ((key & 7) << 4));
    *(short4*)((char*)kws_hi + boff) = make_short4(h[0], h[1], h[2], h[3]);
    *(short4*)((char*)kws_lo + boff) = make_short4(lo[0], lo[1], lo[2], lo[3]);

    float s = f[0]*f[0] + f[1]*f[1] + f[2]*f[2] + f[3]*f[3];
#pragma unroll
    for (int off = 32; off; off >>= 1) s += __shfl_xor(s, off, 64);
    __shared__ float ws[4];
    if ((t & 63) == 0) ws[t >> 6] = s;
    __syncthreads();
    if (t == 0) k2[key] = ws[0] + ws[1] + ws[2] + ws[3];
}

// ---------------------------------------------------------------------------
// Main: block = 32 rows x 256 keys, 4 waves. Wave w: A = ALL 32 rows (regs,
// row = lane&31), B = keys [w*64, w*64+64) (2 tiles of 32) -> each B byte in
// LDS read exactly once per block. mfma_f32_32x32x16_bf16, 3-product split.
// A frag: row=lane&31, k=(lane>>5)*8+i.  B frag: col=lane&31, k=(lane>>5)*8+i.
// C frag: col=lane&31, row=(reg&3)+8*(reg>>2)+4*(lane>>5).
// ---------------------------------------------------------------------------
__global__ __launch_bounds__(256, 2) void vq_mfma32(
        const float* __restrict__ x, const float* __restrict__ keys,
        const unsigned short* __restrict__ kws_hi,
        const unsigned short* __restrict__ kws_lo,
        const float* __restrict__ k2g, const float* __restrict__ values,
        float* __restrict__ out) {
    __shared__ char smem[65536];     // [Bhi 32KB][Blo 32KB]; overlaid later
    char* Bhi = smem;
    char* Blo = smem + 32768;

    const int t = threadIdx.x;
    const int w = t >> 6, l = t & 63;
    const int col = l & 31, hi = l >> 5;
    const int row0 = blockIdx.x * MB;

    f32x16 acc0, acc1;
#pragma unroll
    for (int i = 0; i < 16; ++i) { acc0[i] = 0.f; acc1[i] = 0.f; }

    const float* xrow = x + (size_t)(row0 + col) * C_IN;
    const int key0 = w * 64 + col;            // tile-0 key; tile-1 = key0+32
    const int xorv = (col & 7) << 4;          // == (key&7)<<4 for both tiles
    const int bbase = key0 * 128;

    for (int ch = 0; ch < NCHUNK; ++ch) {
        // ---- stage B chunk (64 KB): wave w copies its 8 KB of hi and of lo
        const char* sH = (const char*)kws_hi + (size_t)ch * 32768 + w * 8192 + l * 16;
        const char* sL = (const char*)kws_lo + (size_t)ch * 32768 + w * 8192 + l * 16;
        char* dH = Bhi + w * 8192;
        char* dL = Blo + w * 8192;
#pragma unroll
        for (int j = 0; j < 8; ++j) {
            load_lds16(sH + j * 1024, dH + j * 1024);
            load_lds16(sL + j * 1024, dL + j * 1024);
        }
        // ---- A: lane's row, k = ch*64 + s*16 + hi*8 + [0..8); hi/lo split
        bf16x8 ah[4], al[4];
#pragma unroll
        for (int s = 0; s < 4; ++s) {
            const float* xp = xrow + ch * KC + s * 16 + hi * 8;
            float4 xa = *(const float4*)xp;
            float4 xb = *(const float4*)(xp + 4);
            float f[8] = {xa.x, xa.y, xa.z, xa.w, xb.x, xb.y, xb.z, xb.w};
#pragma unroll
            for (int i = 0; i < 8; ++i) {
                unsigned short hh = f2bf(f[i]);
                ah[s][i] = (short)hh;
                al[s][i] = (short)f2bf(f[i] - bf2f(hh));
            }
        }
        __syncthreads();   // drains staging; B resident

#pragma unroll
        for (int s = 0; s < 4; ++s) {
            const int kb = bbase + ((s * 32 + hi * 16) ^ xorv);
            bf16x8 bh0 = *(const bf16x8*)(Bhi + kb);
            bf16x8 bl0 = *(const bf16x8*)(Blo + kb);
            acc0 = __builtin_amdgcn_mfma_f32_32x32x16_bf16(ah[s], bh0, acc0, 0, 0, 0);
            acc0 = __builtin_amdgcn_mfma_f32_32x32x16_bf16(ah[s], bl0, acc0, 0, 0, 0);
            acc0 = __builtin_amdgcn_mfma_f32_32x32x16_bf16(al[s], bh0, acc0, 0, 0, 0);
            bf16x8 bh1 = *(const bf16x8*)(Bhi + kb + 4096);   // tile 1: +32 keys
            bf16x8 bl1 = *(const bf16x8*)(Blo + kb + 4096);
            acc1 = __builtin_amdgcn_mfma_f32_32x32x16_bf16(ah[s], bh1, acc1, 0, 0, 0);
            acc1 = __builtin_amdgcn_mfma_f32_32x32x16_bf16(ah[s], bl1, acc1, 0, 0, 0);
            acc1 = __builtin_amdgcn_mfma_f32_32x32x16_bf16(al[s], bh1, acc1, 0, 0, 0);
        }
        __syncthreads();   // all reads done before next chunk overwrite
    }

    // ---- epilogue scratch overlays B (dead after last barrier)
    float*  sv1  = (float*)smem;              // [4][32]
    float*  sv2  = (float*)(smem + 512);      // [4][32]
    int*    si1  = (int*)(smem + 1024);       // [4][32]
    int*    sidx = (int*)(smem + 1536);       // [32]
    float*  sgap = (float*)(smem + 1664);     // [32]
    double* dva  = (double*)(smem + 1792);    // [4]
    int*    dia  = (int*)(smem + 1824);       // [4]

    const float k2A = k2g[key0];
    const float k2B = k2g[key0 + 32];
#pragma unroll
    for (int r = 0; r < 16; ++r) {
        float s0 = k2A - 2.f * acc0[r];
        float s1 = k2B - 2.f * acc1[r];
        float v1, v2; int i1;
        if (s1 < s0) { v1 = s1; i1 = key0 + 32; v2 = s0; }
        else         { v1 = s0; i1 = key0;      v2 = s1; }
#pragma unroll
        for (int off = 1; off < 32; off <<= 1) {   // reduce 32-lane half
            float w1 = __shfl_xor(v1, off, 64);
            int   j1 = __shfl_xor(i1, off, 64);
            float w2 = __shfl_xor(v2, off, 64);
            if (w1 < v1 || (w1 == v1 && j1 < i1)) { v2 = fminf(v1, w2); v1 = w1; i1 = j1; }
            else                                  { v2 = fminf(v2, w1); }
        }
        if (col == 0) {
            const int row = (r & 3) + 8 * (r >> 2) + 4 * hi;
            sv1[w * 32 + row] = v1;
            sv2[w * 32 + row] = v2;
            si1[w * 32 + row] = i1;
        }
    }
    __syncthreads();

    // cross-wave merge (wave key-ranges ascending -> strict < keeps first idx)
    if (t < MB) {
        float v1 = sv1[t], v2 = sv2[t];
        int   i1 = si1[t];
#pragma unroll
        for (int ww = 1; ww < 4; ++ww) {
            float u1 = sv1[ww * 32 + t], u2 = sv2[ww * 32 + t];
            int   ui = si1[ww * 32 + t];
            if (u1 < v1) { v2 = fminf(v1, u2); v1 = u1; i1 = ui; }
            else         { v2 = fminf(v2, u1); }
        }
        sidx[t] = i1;
        sgap[t] = v2 - v1;
    }
    __syncthreads();

    // fp64 refinement for near-tie rows (block-uniform branch; rare)
    const float4* x4 = (const float4*)x;
    for (int fr = 0; fr < MB; ++fr) {
        if (sgap[fr] < TAU) {
            double dotd = 0.0, k2d = 0.0;
            const float4* xr = x4 + (size_t)(row0 + fr) * C4;
            const float4* kr = (const float4*)keys + (size_t)t * C4;
#pragma unroll 4
            for (int c4 = 0; c4 < C4; ++c4) {
                float4 xv = xr[c4];
                float4 kv = kr[c4];
                dotd += (double)kv.x * (double)xv.x; k2d += (double)kv.x * (double)kv.x;
                dotd += (double)kv.y * (double)xv.y; k2d += (double)kv.y * (double)kv.y;
                dotd += (double)kv.z * (double)xv.z; k2d += (double)kv.z * (double)kv.z;
                dotd += (double)kv.w * (double)xv.w; k2d += (double)kv.w * (double)kv.w;
            }
            double sd = k2d - 2.0 * dotd;
            int    si = t;
#pragma unroll
            for (int off = 32; off; off >>= 1) {
                double od = __shfl_xor(sd, off, 64);
                int    oi = __shfl_xor(si, off, 64);
                if (od < sd || (od == sd && oi < si)) { sd = od; si = oi; }
            }
            if (l == 0) { dva[w] = sd; dia[w] = si; }
            __syncthreads();
            if (t == 0) {
                double b = dva[0]; int bi = dia[0];
#pragma unroll
                for (int ww = 1; ww < 4; ++ww)
                    if (dva[ww] < b || (dva[ww] == b && dia[ww] < bi)) { b = dva[ww]; bi = dia[ww]; }
                sidx[fr] = bi;
            }
            __syncthreads();
        }
    }

    // gather values rows -> out (coalesced, 4 KB/row)
    const float4* v4 = (const float4*)values;
    float4* o4 = (float4*)out;
#pragma unroll 4
    for (int r = 0; r < MB; ++r) {
        const int idx = sidx[r];
        o4[(size_t)(row0 + r) * C4 + t] = v4[(size_t)idx * C4 + t];
    }
}

// ---------------------------------------------------------------------------
// Fallback (no/small workspace): round-2 validated fp32 path.
// ---------------------------------------------------------------------------
#define FB_ROWS 16
__global__ __launch_bounds__(256) void codebook_fallback(
    const float* __restrict__ x, const float* __restrict__ keys,
    const float* __restrict__ values, float* __restrict__ out) {
    __shared__ float xs[FB_ROWS * C_IN];
    float4* xs4 = (float4*)xs;
    const int t = threadIdx.x;
    const int row0 = blockIdx.x * FB_ROWS;
    const float4* x4 = (const float4*)x;
#pragma unroll
    for (int i = 0; i < FB_ROWS; ++i)
        xs4[i * C4 + t] = x4[(size_t)row0 * C4 + i * C4 + t];
    __syncthreads();

    float acc[FB_ROWS];
#pragma unroll
    for (int r = 0; r < FB_ROWS; ++r) acc[r] = 0.f;
    float k2acc = 0.f;
    const float4* kptr = ((const float4*)keys) + (size_t)t * C4;
    for (int c4 = 0; c4 < C4; ++c4) {
        float4 kv = kptr[c4];
        k2acc += kv.x * kv.x + kv.y * kv.y + kv.z * kv.z + kv.w * kv.w;
#pragma unroll
        for (int r = 0; r < FB_ROWS; ++r) {
            float4 xv = xs4[r * C4 + c4];
            acc[r] = fmaf(kv.x, xv.x, acc[r]);
            acc[r] = fmaf(kv.y, xv.y, acc[r]);
            acc[r] = fmaf(kv.z, xv.z, acc[r]);
            acc[r] = fmaf(kv.w, xv.w, acc[r]);
        }
    }
    __syncthreads();
    float* ssc  = xs;
    int*   sidx = (int*)(xs + FB_ROWS * KCNT);
    float* sgap = xs + FB_ROWS * KCNT + FB_ROWS;
    double* dva = (double*)(xs + FB_ROWS * KCNT + 2 * FB_ROWS);
    int*    dia = (int*)(xs + FB_ROWS * KCNT + 2 * FB_ROWS + 8);
#pragma unroll
    for (int r = 0; r < FB_ROWS; ++r) ssc[r * KCNT + t] = k2acc - 2.f * acc[r];
    __syncthreads();
    const int wave = t >> 6, lane = t & 63;
#pragma unroll
    for (int i = 0; i < FB_ROWS / 4; ++i) {
        const int r = wave * (FB_ROWS / 4) + i;
        float v1 = ssc[r * KCNT + lane];
        int   i1 = lane;
        float v2 = 1e30f;
#pragma unroll
        for (int j = 1; j < 4; ++j) {
            float c = ssc[r * KCNT + lane + 64 * j];
            if (c < v1) { v2 = v1; v1 = c; i1 = lane + 64 * j; }
            else        { v2 = fminf(v2, c); }
        }
#pragma unroll
        for (int off = 32; off; off >>= 1) {
            float w1 = __shfl_xor(v1, off, 64);
            int   j1 = __shfl_xor(i1, off, 64);
            float w2 = __shfl_xor(v2, off, 64);
            if (w1 < v1 || (w1 == v1 && j1 < i1)) { v2 = fminf(v1, w2); v1 = w1; i1 = j1; }
            else                                  { v2 = fminf(v2, w1); }
        }
        if (lane == 0) { sidx[r] = i1; sgap[r] = v2 - v1; }
    }
    __syncthreads();
    for (int fr = 0; fr < FB_ROWS; ++fr) {
        if (sgap[fr] < 0.02f) {
            double dotd = 0.0, k2d = 0.0;
            const float4* xrow = x4 + (size_t)(row0 + fr) * C4;
#pragma unroll 4
            for (int c4 = 0; c4 < C4; ++c4) {
                float4 xv = xrow[c4];
                float4 kv = ((const float4*)keys)[(size_t)t * C4 + c4];
                dotd += (double)kv.x * (double)xv.x; k2d += (double)kv.x * (double)kv.x;
                dotd += (double)kv.y * (double)xv.y; k2d += (double)kv.y * (double)kv.y;
                dotd += (double)kv.z * (double)xv.z; k2d += (double)kv.z * (double)kv.z;
                dotd += (double)kv.w * (double)xv.w; k2d += (double)kv.w * (double)kv.w;
            }
            double sd = k2d - 2.0 * dotd;
            int    si = t;
#pragma unroll
            for (int off = 32; off; off >>= 1) {
                double od = __shfl_xor(sd, off, 64);
                int    oi = __shfl_xor(si, off, 64);
                if (od < sd || (od == sd && oi < si)) { sd = od; si = oi; }
            }
            if ((t & 63) == 0) { dva[wave] = sd; dia[wave] = si; }
            __syncthreads();
            if (t == 0) {
                double b = dva[0]; int bi = dia[0];
#pragma unroll
                for (int ww = 1; ww < 4; ++ww)
                    if (dva[ww] < b || (dva[ww] == b && dia[ww] < bi)) { b = dva[ww]; bi = dia[ww]; }
                sidx[fr] = bi;
            }
            __syncthreads();
        }
    }
    const float4* v4p = (const float4*)values;
    float4* o4 = (float4*)out;
#pragma unroll
    for (int r = 0; r < FB_ROWS; ++r) {
        const int idx = sidx[r];
        o4[(size_t)(row0 + r) * C4 + t] = v4p[(size_t)idx * C4 + t];
    }
}

extern "C" void kernel_launch(void* const* d_in, const int* in_sizes, int n_in,
                              void* d_out, int out_size, void* d_ws, size_t ws_size,
                              hipStream_t stream) {
    const float* x      = (const float*)d_in[0];
    const float* keys   = (const float*)d_in[1];
    const float* values = (const float*)d_in[2];
    float* out = (float*)d_out;

    const int nrows = in_sizes[0] / C_IN;  // 16384
    const size_t need = 2u * 524288u + 1024u;  // kws_hi + kws_lo + k2

    if (d_ws != nullptr && ws_size >= need && (nrows % MB) == 0) {
        unsigned short* kh = (unsigned short*)d_ws;
        unsigned short* kl = (unsigned short*)((char*)d_ws + 524288);
        float* k2 = (float*)((char*)d_ws + 1048576);
        prep_mfma<<<KCNT, 256, 0, stream>>>(keys, kh, kl, k2);
        vq_mfma32<<<nrows / MB, 256, 0, stream>>>(x, keys, kh, kl, k2, values, out);
    } else {
        codebook_fallback<<<nrows / FB_ROWS, 256, 0, stream>>>(x, keys, values, out);
    }
}

// Round 5
// 145.369 us; speedup vs baseline: 1.0359x; 1.0359x over previous
//
#include <hip/hip_runtime.h>

#define C_IN   1024
#define C4     (C_IN / 4)      // 256 float4 per row (also C_out/4)
#define KCNT   256
#define TAU    0.05f           // split-bf16 score error ~4e-3 worst -> >10x margin
#define MB     16              // x-rows per block -> grid 1024, LDS 64KB, 2 blk/CU

typedef __attribute__((ext_vector_type(8))) short bf16x8;
typedef __attribute__((ext_vector_type(4))) float f32x4;

static __device__ __forceinline__ unsigned short f2bf(float f) {
    union { float f; unsigned u; } v; v.f = f;
    unsigned r = v.u + 0x7fffu + ((v.u >> 16) & 1u);   // RNE
    return (unsigned short)(r >> 16);
}
static __device__ __forceinline__ unsigned short f2bf_t(float f) {  // truncate
    union { float f; unsigned u; } v; v.f = f;
    return (unsigned short)(v.u >> 16);
}
static __device__ __forceinline__ float bf2f(unsigned short h) {
    union { unsigned u; float f; } v; v.u = (unsigned)h << 16;
    return v.f;
}

// ---------------------------------------------------------------------------
// Prep: keys -> hi/lo bf16 images laid out in the EXACT per-wave load order of
// the main kernel: fragment block (kt,cc) is 1KB contiguous; lane l holds
// key = kt*16 + (l&15), c = cc*32 + (l>>4)*8 + [0,8).  Also k2[key] (fp32).
// Thread t of block `key` covers c = 4t..4t+3:
//   addr = ((key>>4)*32 + (t>>3))*1024 + ((key&15) + 16*((t>>1)&3))*16 + (t&1)*8
// ---------------------------------------------------------------------------
__global__ __launch_bounds__(256) void prep_mfma(const float* __restrict__ keys,
        unsigned short* __restrict__ bhi, unsigned short* __restrict__ blo,
        float* __restrict__ k2) {
    const int key = blockIdx.x, t = threadIdx.x;
    float4 v = ((const float4*)keys)[(size_t)key * C4 + t];
    float f[4] = {v.x, v.y, v.z, v.w};
    unsigned short h[4], lo[4];
#pragma unroll
    for (int i = 0; i < 4; ++i) {
        h[i]  = f2bf(f[i]);
        lo[i] = f2bf(f[i] - bf2f(h[i]));   // exact residual, RNE
    }
    const size_t addr = ((size_t)(key >> 4) * 32 + (t >> 3)) * 1024
                      + (size_t)(((key & 15) + (((t >> 1) & 3) << 4)) << 4)
                      + (size_t)((t & 1) * 8);
    *(ushort4*)((char*)bhi + addr) = make_ushort4(h[0], h[1], h[2], h[3]);
    *(ushort4*)((char*)blo + addr) = make_ushort4(lo[0], lo[1], lo[2], lo[3]);

    float s = f[0]*f[0] + f[1]*f[1] + f[2]*f[2] + f[3]*f[3];
#pragma unroll
    for (int off = 32; off; off >>= 1) s += __shfl_xor(s, off, 64);
    __shared__ float ws[4];
    if ((t & 63) == 0) ws[t >> 6] = s;
    __syncthreads();
    if (t == 0) k2[key] = ws[0] + ws[1] + ws[2] + ws[3];
}

// ---------------------------------------------------------------------------
// Main: block = 16 rows x 256 keys, 4 waves. X resident in LDS (hi/lo bf16,
// XOR-swizzled); wave w streams its 64 keys (tiles kt=w*4..w*4+3) from the
// global image into a register ring. NO barriers in the K-loop.
// mfma_f32_16x16x32_bf16; A: row=lane&15, k=(lane>>4)*8+i (from LDS);
// B: col(key)=lane&15, same k (from global); C: col=lane&15, row=(lane>>4)*4+r.
// Split product: acch += ah*bh ; accl += ah*bl ; accl += al*bh (8 indep chains).
// ---------------------------------------------------------------------------
__global__ __launch_bounds__(256, 2) void vq_keystream(
        const float* __restrict__ x, const float* __restrict__ keys,
        const unsigned short* __restrict__ bhi,
        const unsigned short* __restrict__ blo,
        const float* __restrict__ k2g, const float* __restrict__ values,
        float* __restrict__ out) {
    __shared__ char smem[65536];     // Xhi [0,32K) + Xlo [32K,64K); overlaid later
    char* Xhi = smem;
    char* Xlo = smem + 32768;

    const int t = threadIdx.x;
    const int w = t >> 6, l = t & 63;
    const int l15 = l & 15, lg = l >> 4;
    const int row0 = blockIdx.x * MB;

    const char* bH = (const char*)bhi;
    const char* bL = (const char*)blo;

    // B fragment byte address for this lane, tile j (wave-owned), chunk cc
#define BADDR(j, cc) ((size_t)((((w * 4 + (j)) * 32 + (cc)) << 10) + (l << 4)))
    bf16x8 B0h[4], B0l[4], B1h[4], B1l[4], B2h[4], B2l[4], B3h[4], B3l[4];
#define LOADB(buf, cc) do { _Pragma("unroll") \
    for (int j = 0; j < 4; ++j) { \
        buf##h[j] = *(const bf16x8*)(bH + BADDR(j, (cc))); \
        buf##l[j] = *(const bf16x8*)(bL + BADDR(j, (cc))); } } while (0)

    // issue first prefetches BEFORE staging (L2 latency hides under staging)
    LOADB(B0, 0); LOADB(B1, 1); LOADB(B2, 2);

    // ---- stage x tile: 4096 float4 coalesced; hi/lo bf16, swizzled rows
    {
        const float4* x4 = (const float4*)(x + (size_t)row0 * C_IN);
#pragma unroll
        for (int i = 0; i < 16; ++i) {
            const int idx = i * 256 + t;         // flat float4 index
            float4 v = x4[idx];
            const int row = idx >> 8;
            const int cb  = (idx & 255) * 8;     // byte offset (c*2) in row
            const int off = row * 2048 + (cb ^ ((row & 7) << 4));
            *(ushort4*)(Xhi + off) = make_ushort4(f2bf(v.x), f2bf(v.y),
                                                  f2bf(v.z), f2bf(v.w));
            *(ushort4*)(Xlo + off) = make_ushort4(
                f2bf_t(v.x - bf2f(f2bf(v.x))), f2bf_t(v.y - bf2f(f2bf(v.y))),
                f2bf_t(v.z - bf2f(f2bf(v.z))), f2bf_t(v.w - bf2f(f2bf(v.w))));
        }
    }
    __syncthreads();   // the ONLY pre-epilogue barrier; LDS read-only after

    // A fragment LDS address (validated 8-slot XOR swizzle: 2-way = free)
    const int abase = l15 * 2048;
    const int asw   = (l15 & 7) << 4;
#define AADDR(cc) (abase + (((((cc) << 6)) + (lg << 4)) ^ asw))
    bf16x8 A0h, A0l, A1h, A1l;
#define LOADA(buf, cc) do { \
    buf##h = *(const bf16x8*)(Xhi + AADDR(cc)); \
    buf##l = *(const bf16x8*)(Xlo + AADDR(cc)); } while (0)
    LOADA(A0, 0); LOADA(A1, 1);

    f32x4 acch[4], accl[4];
#pragma unroll
    for (int j = 0; j < 4; ++j) {
        acch[j] = (f32x4){0.f, 0.f, 0.f, 0.f};
        accl[j] = (f32x4){0.f, 0.f, 0.f, 0.f};
    }
#define MFMA_CC(Ab, Bb) do { _Pragma("unroll") \
    for (int j = 0; j < 4; ++j) { \
        acch[j] = __builtin_amdgcn_mfma_f32_16x16x32_bf16(Ab##h, Bb##h[j], acch[j], 0, 0, 0); \
        accl[j] = __builtin_amdgcn_mfma_f32_16x16x32_bf16(Ab##h, Bb##l[j], accl[j], 0, 0, 0); \
        accl[j] = __builtin_amdgcn_mfma_f32_16x16x32_bf16(Ab##l, Bb##h[j], accl[j], 0, 0, 0); } } while (0)

    // ---- barrier-free K loop: 32 chunks, 4 per iteration, ring prefetch
#pragma unroll
    for (int q = 0; q < 8; ++q) {
        const int cc = q * 4;
        LOADB(B3, cc + 3);                    // always valid (<=31)
        MFMA_CC(A0, B0);                      // cc
        LOADA(A0, cc + 2);                    // always valid (<=30)
        if (q < 7) LOADB(B0, cc + 4);
        MFMA_CC(A1, B1);                      // cc+1
        LOADA(A1, cc + 3);                    // always valid (<=31)
        if (q < 7) LOADB(B1, cc + 5);
        MFMA_CC(A0, B2);                      // cc+2
        if (q < 7) LOADA(A0, cc + 4);
        if (q < 7) LOADB(B2, cc + 6);
        MFMA_CC(A1, B3);                      // cc+3
        if (q < 7) LOADA(A1, cc + 5);
    }

    __syncthreads();   // all LDS A-reads done -> safe to overlay scratch
    float*  sv1  = (float*)smem;              // [4][16]
    float*  sv2  = (float*)(smem + 256);      // [4][16]
    int*    si1  = (int*)(smem + 512);        // [4][16]
    int*    sidx = (int*)(smem + 768);        // [16]
    float*  sgap = (float*)(smem + 832);      // [16]
    double* dva  = (double*)(smem + 896);     // [4]
    int*    dia  = (int*)(smem + 928);        // [4]

    float k2w[4];
#pragma unroll
    for (int j = 0; j < 4; ++j) k2w[j] = k2g[(w * 4 + j) * 16 + l15];

    // per-(lane,reg) top-2 over the wave's 4 key-tiles, then 16-lane reduce
#pragma unroll
    for (int r = 0; r < 4; ++r) {
        float v1 = 1e30f, v2 = 1e30f; int i1 = 0;
#pragma unroll
        for (int j = 0; j < 4; ++j) {         // keys ascending in j
            float s = k2w[j] - 2.f * (acch[j][r] + accl[j][r]);
            if (s < v1) { v2 = v1; v1 = s; i1 = (w * 4 + j) * 16 + l15; }
            else        { v2 = fminf(v2, s); }
        }
#pragma unroll
        for (int off = 1; off < 16; off <<= 1) {
            float w1 = __shfl_xor(v1, off, 64);
            int   j1 = __shfl_xor(i1, off, 64);
            float w2 = __shfl_xor(v2, off, 64);
            if (w1 < v1 || (w1 == v1 && j1 < i1)) { v2 = fminf(v1, w2); v1 = w1; i1 = j1; }
            else                                  { v2 = fminf(v2, w1); }
        }
        if (l15 == 0) {
            const int row = lg * 4 + r;
            sv1[w * 16 + row] = v1; sv2[w * 16 + row] = v2; si1[w * 16 + row] = i1;
        }
    }
    __syncthreads();

    // cross-wave merge (wave key ranges ascending; idx tie-break for safety)
    if (t < MB) {
        float v1 = sv1[t], v2 = sv2[t]; int i1 = si1[t];
#pragma unroll
        for (int ww = 1; ww < 4; ++ww) {
            float u1 = sv1[ww * 16 + t], u2 = sv2[ww * 16 + t];
            int   ui = si1[ww * 16 + t];
            if (u1 < v1 || (u1 == v1 && ui < i1)) { v2 = fminf(v1, u2); v1 = u1; i1 = ui; }
            else                                  { v2 = fminf(v2, u1); }
        }
        sidx[t] = i1; sgap[t] = v2 - v1;
    }
    __syncthreads();

    // fp64 refinement for near-tie rows (block-uniform branch; ~0.3% of rows)
    const float4* x4r = (const float4*)x;
    for (int fr = 0; fr < MB; ++fr) {
        if (sgap[fr] < TAU) {
            double dotd = 0.0, k2d = 0.0;
            const float4* xr = x4r + (size_t)(row0 + fr) * C4;
            const float4* kr = (const float4*)keys + (size_t)t * C4;
#pragma unroll 4
            for (int c4 = 0; c4 < C4; ++c4) {
                float4 xv = xr[c4];
                float4 kv = kr[c4];
                dotd += (double)kv.x * (double)xv.x; k2d += (double)kv.x * (double)kv.x;
                dotd += (double)kv.y * (double)xv.y; k2d += (double)kv.y * (double)kv.y;
                dotd += (double)kv.z * (double)xv.z; k2d += (double)kv.z * (double)kv.z;
                dotd += (double)kv.w * (double)xv.w; k2d += (double)kv.w * (double)kv.w;
            }
            double sd = k2d - 2.0 * dotd;
            int    si = t;
#pragma unroll
            for (int off = 32; off; off >>= 1) {
                double od = __shfl_xor(sd, off, 64);
                int    oi = __shfl_xor(si, off, 64);
                if (od < sd || (od == sd && oi < si)) { sd = od; si = oi; }
            }
            if (l == 0) { dva[w] = sd; dia[w] = si; }
            __syncthreads();
            if (t == 0) {
                double b = dva[0]; int bi = dia[0];
#pragma unroll
                for (int ww = 1; ww < 4; ++ww)
                    if (dva[ww] < b || (dva[ww] == b && dia[ww] < bi)) { b = dva[ww]; bi = dia[ww]; }
                sidx[fr] = bi;
            }
            __syncthreads();
        }
    }

    // gather values rows -> out (coalesced, 4 KB/row)
    const float4* v4 = (const float4*)values;
    float4* o4 = (float4*)out;
#pragma unroll
    for (int r = 0; r < MB; ++r) {
        const int idx = sidx[r];
        o4[(size_t)(row0 + r) * C4 + t] = v4[(size_t)idx * C4 + t];
    }
#undef BADDR
#undef LOADB
#undef AADDR
#undef LOADA
#undef MFMA_CC
}

// ---------------------------------------------------------------------------
// Fallback (no/small workspace): round-2 validated fp32 path.
// ---------------------------------------------------------------------------
#define FB_ROWS 16
__global__ __launch_bounds__(256) void codebook_fallback(
    const float* __restrict__ x, const float* __restrict__ keys,
    const float* __restrict__ values, float* __restrict__ out) {
    __shared__ float xs[FB_ROWS * C_IN];
    float4* xs4 = (float4*)xs;
    const int t = threadIdx.x;
    const int row0 = blockIdx.x * FB_ROWS;
    const float4* x4 = (const float4*)x;
#pragma unroll
    for (int i = 0; i < FB_ROWS; ++i)
        xs4[i * C4 + t] = x4[(size_t)row0 * C4 + i * C4 + t];
    __syncthreads();

    float acc[FB_ROWS];
#pragma unroll
    for (int r = 0; r < FB_ROWS; ++r) acc[r] = 0.f;
    float k2acc = 0.f;
    const float4* kptr = ((const float4*)keys) + (size_t)t * C4;
    for (int c4 = 0; c4 < C4; ++c4) {
        float4 kv = kptr[c4];
        k2acc += kv.x * kv.x + kv.y * kv.y + kv.z * kv.z + kv.w * kv.w;
#pragma unroll
        for (int r = 0; r < FB_ROWS; ++r) {
            float4 xv = xs4[r * C4 + c4];
            acc[r] = fmaf(kv.x, xv.x, acc[r]);
            acc[r] = fmaf(kv.y, xv.y, acc[r]);
            acc[r] = fmaf(kv.z, xv.z, acc[r]);
            acc[r] = fmaf(kv.w, xv.w, acc[r]);
        }
    }
    __syncthreads();
    float* ssc  = xs;
    int*   sidx = (int*)(xs + FB_ROWS * KCNT);
    float* sgap = xs + FB_ROWS * KCNT + FB_ROWS;
    double* dva = (double*)(xs + FB_ROWS * KCNT + 2 * FB_ROWS);
    int*    dia = (int*)(xs + FB_ROWS * KCNT + 2 * FB_ROWS + 8);
#pragma unroll
    for (int r = 0; r < FB_ROWS; ++r) ssc[r * KCNT + t] = k2acc - 2.f * acc[r];
    __syncthreads();
    const int wave = t >> 6, lane = t & 63;
#pragma unroll
    for (int i = 0; i < FB_ROWS / 4; ++i) {
        const int r = wave * (FB_ROWS / 4) + i;
        float v1 = ssc[r * KCNT + lane];
        int   i1 = lane;
        float v2 = 1e30f;
#pragma unroll
        for (int j = 1; j < 4; ++j) {
            float c = ssc[r * KCNT + lane + 64 * j];
            if (c < v1) { v2 = v1; v1 = c; i1 = lane + 64 * j; }
            else        { v2 = fminf(v2, c); }
        }
#pragma unroll
        for (int off = 32; off; off >>= 1) {
            float w1 = __shfl_xor(v1, off, 64);
            int   j1 = __shfl_xor(i1, off, 64);
            float w2 = __shfl_xor(v2, off, 64);
            if (w1 < v1 || (w1 == v1 && j1 < i1)) { v2 = fminf(v1, w2); v1 = w1; i1 = j1; }
            else                                  { v2 = fminf(v2, w1); }
        }
        if (lane == 0) { sidx[r] = i1; sgap[r] = v2 - v1; }
    }
    __syncthreads();
    for (int fr = 0; fr < FB_ROWS; ++fr) {
        if (sgap[fr] < 0.02f) {
            double dotd = 0.0, k2d = 0.0;
            const float4* xrow = x4 + (size_t)(row0 + fr) * C4;
#pragma unroll 4
            for (int c4 = 0; c4 < C4; ++c4) {
                float4 xv = xrow[c4];
                float4 kv = ((const float4*)keys)[(size_t)t * C4 + c4];
                dotd += (double)kv.x * (double)xv.x; k2d += (double)kv.x * (double)kv.x;
                dotd += (double)kv.y * (double)xv.y; k2d += (double)kv.y * (double)kv.y;
                dotd += (double)kv.z * (double)xv.z; k2d += (double)kv.z * (double)kv.z;
                dotd += (double)kv.w * (double)xv.w; k2d += (double)kv.w * (double)kv.w;
            }
            double sd = k2d - 2.0 * dotd;
            int    si = t;
#pragma unroll
            for (int off = 32; off; off >>= 1) {
                double od = __shfl_xor(sd, off, 64);
                int    oi = __shfl_xor(si, off, 64);
                if (od < sd || (od == sd && oi < si)) { sd = od; si = oi; }
            }
            if ((t & 63) == 0) { dva[wave] = sd; dia[wave] = si; }
            __syncthreads();
            if (t == 0) {
                double b = dva[0]; int bi = dia[0];
#pragma unroll
                for (int ww = 1; ww < 4; ++ww)
                    if (dva[ww] < b || (dva[ww] == b && dia[ww] < bi)) { b = dva[ww]; bi = dia[ww]; }
                sidx[fr] = bi;
            }
            __syncthreads();
        }
    }
    const float4* v4p = (const float4*)values;
    float4* o4 = (float4*)out;
#pragma unroll
    for (int r = 0; r < FB_ROWS; ++r) {
        const int idx = sidx[r];
        o4[(size_t)(row0 + r) * C4 + t] = v4p[(size_t)idx * C4 + t];
    }
}

extern "C" void kernel_launch(void* const* d_in, const int* in_sizes, int n_in,
                              void* d_out, int out_size, void* d_ws, size_t ws_size,
                              hipStream_t stream) {
    const float* x      = (const float*)d_in[0];
    const float* keys   = (const float*)d_in[1];
    const float* values = (const float*)d_in[2];
    float* out = (float*)d_out;

    const int nrows = in_sizes[0] / C_IN;  // 16384
    const size_t need = 2u * 524288u + 1024u;  // bhi + blo + k2

    if (d_ws != nullptr && ws_size >= need && (nrows % MB) == 0) {
        unsigned short* bh = (unsigned short*)d_ws;
        unsigned short* bl = (unsigned short*)((char*)d_ws + 524288);
        float* k2 = (float*)((char*)d_ws + 1048576);
        prep_mfma<<<KCNT, 256, 0, stream>>>(keys, bh, bl, k2);
        vq_keystream<<<nrows / MB, 256, 0, stream>>>(x, keys, bh, bl, k2, values, out);
    } else {
        codebook_fallback<<<nrows / FB_ROWS, 256, 0, stream>>>(x, keys, values, out);
    }
}

// Round 6
// 132.564 us; speedup vs baseline: 1.1359x; 1.0966x over previous
//
#include <hip/hip_runtime.h>

#define C_IN   1024
#define C4     (C_IN / 4)      // 256 float4 per row (also C_out/4)
#define KCNT   256
#define TAU    0.05f           // split-bf16 score err ~4e-3 -> >10x margin
#define MB     32              // rows/block -> grid 512, 2 blocks/CU
#define NCH    32              // K chunks of 32 dims

typedef __attribute__((ext_vector_type(8))) short bf16x8;
typedef __attribute__((ext_vector_type(4))) float f32x4;

static __device__ __forceinline__ unsigned short f2bf(float f) {
    union { float f; unsigned u; } v; v.f = f;
    unsigned r = v.u + 0x7fffu + ((v.u >> 16) & 1u);   // RNE
    return (unsigned short)(r >> 16);
}
static __device__ __forceinline__ float bf2f(unsigned short h) {
    union { unsigned u; float f; } v; v.u = (unsigned)h << 16;
    return v.f;
}
static __device__ __forceinline__ void load_lds16(const void* g, void* l) {
    __builtin_amdgcn_global_load_lds(
        (const __attribute__((address_space(1))) unsigned int*)g,
        (__attribute__((address_space(3))) unsigned int*)l, 16, 0, 0);
}
static __device__ __forceinline__ void cvt8(float4 a, float4 b,
                                            bf16x8& h8, bf16x8& l8) {
    float f[8] = {a.x, a.y, a.z, a.w, b.x, b.y, b.z, b.w};
#pragma unroll
    for (int i = 0; i < 8; ++i) {
        unsigned short hh = f2bf(f[i]);
        h8[i] = (short)hh;
        l8[i] = (short)f2bf(f[i] - bf2f(hh));   // exact residual
    }
}

// ---------------------------------------------------------------------------
// Prep: keys -> 1 MB chunk-major hi/lo bf16 image matching the main kernel's
// LDS layout exactly: chunk c (32 KB) -> key-tile kt (2 KB) -> [hi 1KB|lo 1KB],
// 1 KB lane-ordered: lane l = (key&15) + 16*(dim_in_chunk>>3), 16 B = 8 dims.
// Thread t of key-block k covers dims 4t..4t+3. Also k2[key] = ||key||^2.
// ---------------------------------------------------------------------------
__global__ __launch_bounds__(256) void prep_img(const float* __restrict__ keys,
        unsigned short* __restrict__ img, float* __restrict__ k2) {
    const int k = blockIdx.x, t = threadIdx.x;
    float4 v = ((const float4*)keys)[(size_t)k * C4 + t];
    float f[4] = {v.x, v.y, v.z, v.w};
    unsigned short h[4], lo[4];
#pragma unroll
    for (int i = 0; i < 4; ++i) {
        h[i]  = f2bf(f[i]);
        lo[i] = f2bf(f[i] - bf2f(h[i]));
    }
    const int c    = t >> 3;           // chunk = 4t/32
    const int dd   = (4 * t) & 31;     // dim-in-chunk (0,4,8,...,28)
    const int lane = (k & 15) + ((dd >> 3) << 4);
    const size_t addr = (size_t)c * 32768 + (size_t)(k >> 4) * 2048
                      + (size_t)lane * 16 + (size_t)(dd & 7) * 2;
    *(ushort4*)((char*)img + addr)        = make_ushort4(h[0], h[1], h[2], h[3]);
    *(ushort4*)((char*)img + addr + 1024) = make_ushort4(lo[0], lo[1], lo[2], lo[3]);

    float s = f[0]*f[0] + f[1]*f[1] + f[2]*f[2] + f[3]*f[3];
#pragma unroll
    for (int off = 32; off; off >>= 1) s += __shfl_xor(s, off, 64);
    __shared__ float ws[4];
    if ((t & 63) == 0) ws[t >> 6] = s;
    __syncthreads();
    if (t == 0) k2[k] = ws[0] + ws[1] + ws[2] + ws[3];
}

// ---------------------------------------------------------------------------
// Main: block = 32 rows x 256 keys, 4 waves; wave w owns key-tiles w*4..w*4+3.
// Keys: 2-deep LDS chunk double-buffer filled by global_load_lds DMA; counted
// vmcnt(12) per iter (8 DMA + 4 A-loads issued/iter => vmcnt(12) == "all prior
// iters done"), raw s_barrier pairs, NEVER vmcnt(0) in steady state.
// A (x rows): global->reg ping-pong one chunk ahead, hi/lo bf16 conversion.
// mfma_f32_16x16x32_bf16, 3-product split (validated r3/r5).
// C layout: col(key)=lane&15, row=(lane>>4)*4+reg (validated r5, absmax 0).
// ---------------------------------------------------------------------------
__global__ __launch_bounds__(256, 2) void vq_pipe(
        const float* __restrict__ x, const float* __restrict__ keys,
        const unsigned short* __restrict__ img,
        const float* __restrict__ k2g, const float* __restrict__ values,
        float* __restrict__ out) {
    __shared__ char smem[65536];     // 2 x 32 KB chunk buffers; overlaid later

    const int t = threadIdx.x;
    const int w = t >> 6, l = t & 63;
    const int l15 = l & 15, lg = l >> 4;
    const int row0 = blockIdx.x * MB;

    f32x4 acch[2][4], accl[2][4];
#pragma unroll
    for (int rt = 0; rt < 2; ++rt)
#pragma unroll
        for (int j = 0; j < 4; ++j) {
            acch[rt][j] = (f32x4){0.f, 0.f, 0.f, 0.f};
            accl[rt][j] = (f32x4){0.f, 0.f, 0.f, 0.f};
        }

    const char* src = (const char*)img;
    const int soff = w * 8192 + l * 16;            // wave's staging slice

    // A-row pointers for the two row-tiles (lane -> row l15 / 16+l15, k lg*8)
    const float* xr0 = x + (size_t)(row0 + l15) * C_IN + lg * 8;
    const float* xr1 = x + (size_t)(row0 + 16 + l15) * C_IN + lg * 8;

    // ---- prologue: stage chunk 0, load A chunk 0
    {
        const char* s = src + soff;
        char* d = smem + soff;
#pragma unroll
        for (int j = 0; j < 8; ++j) load_lds16(s + j * 1024, d + j * 1024);
    }
    float4 p00 = *(const float4*)(xr0);
    float4 p01 = *(const float4*)(xr0 + 4);
    float4 p10 = *(const float4*)(xr1);
    float4 p11 = *(const float4*)(xr1 + 4);

#pragma unroll 1
    for (int c = 0; c < NCH; ++c) {
        char* bufc = smem + ((c & 1) << 15);
        float4 n00, n01, n10, n11;
        const bool more = (c < NCH - 1);
        if (more) {
            const char* s = src + (size_t)(c + 1) * 32768 + soff;
            char* d = smem + (((c + 1) & 1) << 15) + soff;
#pragma unroll
            for (int j = 0; j < 8; ++j) load_lds16(s + j * 1024, d + j * 1024);
            n00 = *(const float4*)(xr0 + (c + 1) * 32);
            n01 = *(const float4*)(xr0 + (c + 1) * 32 + 4);
            n10 = *(const float4*)(xr1 + (c + 1) * 32);
            n11 = *(const float4*)(xr1 + (c + 1) * 32 + 4);
        }
        // convert A_c (compiler's dependency wait == counted vmcnt, not drain)
        bf16x8 ah0, al0, ah1, al1;
        cvt8(p00, p01, ah0, al0);
        cvt8(p10, p11, ah1, al1);

        if (more) { asm volatile("s_waitcnt vmcnt(12)" ::: "memory"); }
        else      { asm volatile("s_waitcnt vmcnt(0)"  ::: "memory"); }
        __builtin_amdgcn_sched_barrier(0);
        __builtin_amdgcn_s_barrier();          // chunk c resident for all waves
        __builtin_amdgcn_sched_barrier(0);

#pragma unroll
        for (int j = 0; j < 4; ++j) {
            const char* bp = bufc + ((w * 4 + j) << 11) + (l << 4);
            bf16x8 bh = *(const bf16x8*)bp;            // conflict-free 1KB read
            bf16x8 bl = *(const bf16x8*)(bp + 1024);
            acch[0][j] = __builtin_amdgcn_mfma_f32_16x16x32_bf16(ah0, bh, acch[0][j], 0, 0, 0);
            accl[0][j] = __builtin_amdgcn_mfma_f32_16x16x32_bf16(ah0, bl, accl[0][j], 0, 0, 0);
            accl[0][j] = __builtin_amdgcn_mfma_f32_16x16x32_bf16(al0, bh, accl[0][j], 0, 0, 0);
            acch[1][j] = __builtin_amdgcn_mfma_f32_16x16x32_bf16(ah1, bh, acch[1][j], 0, 0, 0);
            accl[1][j] = __builtin_amdgcn_mfma_f32_16x16x32_bf16(ah1, bl, accl[1][j], 0, 0, 0);
            accl[1][j] = __builtin_amdgcn_mfma_f32_16x16x32_bf16(al1, bh, accl[1][j], 0, 0, 0);
        }
        __builtin_amdgcn_sched_barrier(0);
        __builtin_amdgcn_s_barrier();          // all reads done before overwrite
        __builtin_amdgcn_sched_barrier(0);

        if (more) { p00 = n00; p01 = n01; p10 = n10; p11 = n11; }
    }
    __syncthreads();

    // ---- epilogue scratch overlays buffers (dead now)
    float*  sv1  = (float*)smem;              // [4][32]
    float*  sv2  = (float*)(smem + 512);      // [4][32]
    int*    si1  = (int*)(smem + 1024);       // [4][32]
    int*    sidx = (int*)(smem + 1536);       // [32]
    float*  sgap = (float*)(smem + 1664);     // [32]
    double* dva  = (double*)(smem + 1792);    // [4]
    int*    dia  = (int*)(smem + 1824);       // [4]

    float k2w[4];
#pragma unroll
    for (int j = 0; j < 4; ++j) k2w[j] = k2g[(w * 4 + j) * 16 + l15];

    // top-2 per row: scan j ascending (keys ascending), 16-lane shuffle reduce
#pragma unroll
    for (int rt = 0; rt < 2; ++rt) {
#pragma unroll
        for (int r = 0; r < 4; ++r) {
            float v1 = 1e30f, v2 = 1e30f; int i1 = 0;
#pragma unroll
            for (int j = 0; j < 4; ++j) {
                float s = k2w[j] - 2.f * (acch[rt][j][r] + accl[rt][j][r]);
                if (s < v1) { v2 = v1; v1 = s; i1 = (w * 4 + j) * 16 + l15; }
                else        { v2 = fminf(v2, s); }
            }
#pragma unroll
            for (int off = 1; off < 16; off <<= 1) {
                float w1 = __shfl_xor(v1, off, 64);
                int   j1 = __shfl_xor(i1, off, 64);
                float w2 = __shfl_xor(v2, off, 64);
                if (w1 < v1 || (w1 == v1 && j1 < i1)) { v2 = fminf(v1, w2); v1 = w1; i1 = j1; }
                else                                  { v2 = fminf(v2, w1); }
            }
            if (l15 == 0) {
                const int row = rt * 16 + lg * 4 + r;
                sv1[w * 32 + row] = v1; sv2[w * 32 + row] = v2; si1[w * 32 + row] = i1;
            }
        }
    }
    __syncthreads();

    // cross-wave merge (wave key ranges ascending; idx tie-break)
    if (t < MB) {
        float v1 = sv1[t], v2 = sv2[t]; int i1 = si1[t];
#pragma unroll
        for (int ww = 1; ww < 4; ++ww) {
            float u1 = sv1[ww * 32 + t], u2 = sv2[ww * 32 + t];
            int   ui = si1[ww * 32 + t];
            if (u1 < v1 || (u1 == v1 && ui < i1)) { v2 = fminf(v1, u2); v1 = u1; i1 = ui; }
            else                                  { v2 = fminf(v2, u1); }
        }
        sidx[t] = i1; sgap[t] = v2 - v1;
    }
    __syncthreads();

    // fp64 refinement for near-tie rows (block-uniform branch; ~0.3% of rows)
    const float4* x4r = (const float4*)x;
    for (int fr = 0; fr < MB; ++fr) {
        if (sgap[fr] < TAU) {
            double dotd = 0.0, k2d = 0.0;
            const float4* xr = x4r + (size_t)(row0 + fr) * C4;
            const float4* kr = (const float4*)keys + (size_t)t * C4;
#pragma unroll 4
            for (int c4 = 0; c4 < C4; ++c4) {
                float4 xv = xr[c4];
                float4 kv = kr[c4];
                dotd += (double)kv.x * (double)xv.x; k2d += (double)kv.x * (double)kv.x;
                dotd += (double)kv.y * (double)xv.y; k2d += (double)kv.y * (double)kv.y;
                dotd += (double)kv.z * (double)xv.z; k2d += (double)kv.z * (double)kv.z;
                dotd += (double)kv.w * (double)xv.w; k2d += (double)kv.w * (double)kv.w;
            }
            double sd = k2d - 2.0 * dotd;
            int    si = t;
#pragma unroll
            for (int off = 32; off; off >>= 1) {
                double od = __shfl_xor(sd, off, 64);
                int    oi = __shfl_xor(si, off, 64);
                if (od < sd || (od == sd && oi < si)) { sd = od; si = oi; }
            }
            if (l == 0) { dva[w] = sd; dia[w] = si; }
            __syncthreads();
            if (t == 0) {
                double b = dva[0]; int bi = dia[0];
#pragma unroll
                for (int ww = 1; ww < 4; ++ww)
                    if (dva[ww] < b || (dva[ww] == b && dia[ww] < bi)) { b = dva[ww]; bi = dia[ww]; }
                sidx[fr] = bi;
            }
            __syncthreads();
        }
    }

    // gather values rows -> out (coalesced, 4 KB/row)
    const float4* v4 = (const float4*)values;
    float4* o4 = (float4*)out;
#pragma unroll 4
    for (int r = 0; r < MB; ++r) {
        const int idx = sidx[r];
        o4[(size_t)(row0 + r) * C4 + t] = v4[(size_t)idx * C4 + t];
    }
}

// ---------------------------------------------------------------------------
// Fallback (no/small workspace): round-2 validated fp32 path.
// ---------------------------------------------------------------------------
#define FB_ROWS 16
__global__ __launch_bounds__(256) void codebook_fallback(
    const float* __restrict__ x, const float* __restrict__ keys,
    const float* __restrict__ values, float* __restrict__ out) {
    __shared__ float xs[FB_ROWS * C_IN];
    float4* xs4 = (float4*)xs;
    const int t = threadIdx.x;
    const int row0 = blockIdx.x * FB_ROWS;
    const float4* x4 = (const float4*)x;
#pragma unroll
    for (int i = 0; i < FB_ROWS; ++i)
        xs4[i * C4 + t] = x4[(size_t)row0 * C4 + i * C4 + t];
    __syncthreads();

    float acc[FB_ROWS];
#pragma unroll
    for (int r = 0; r < FB_ROWS; ++r) acc[r] = 0.f;
    float k2acc = 0.f;
    const float4* kptr = ((const float4*)keys) + (size_t)t * C4;
    for (int c4 = 0; c4 < C4; ++c4) {
        float4 kv = kptr[c4];
        k2acc += kv.x * kv.x + kv.y * kv.y + kv.z * kv.z + kv.w * kv.w;
#pragma unroll
        for (int r = 0; r < FB_ROWS; ++r) {
            float4 xv = xs4[r * C4 + c4];
            acc[r] = fmaf(kv.x, xv.x, acc[r]);
            acc[r] = fmaf(kv.y, xv.y, acc[r]);
            acc[r] = fmaf(kv.z, xv.z, acc[r]);
            acc[r] = fmaf(kv.w, xv.w, acc[r]);
        }
    }
    __syncthreads();
    float* ssc  = xs;
    int*   sidx = (int*)(xs + FB_ROWS * KCNT);
    float* sgap = xs + FB_ROWS * KCNT + FB_ROWS;
    double* dva = (double*)(xs + FB_ROWS * KCNT + 2 * FB_ROWS);
    int*    dia = (int*)(xs + FB_ROWS * KCNT + 2 * FB_ROWS + 8);
#pragma unroll
    for (int r = 0; r < FB_ROWS; ++r) ssc[r * KCNT + t] = k2acc - 2.f * acc[r];
    __syncthreads();
    const int wave = t >> 6, lane = t & 63;
#pragma unroll
    for (int i = 0; i < FB_ROWS / 4; ++i) {
        const int r = wave * (FB_ROWS / 4) + i;
        float v1 = ssc[r * KCNT + lane];
        int   i1 = lane;
        float v2 = 1e30f;
#pragma unroll
        for (int j = 1; j < 4; ++j) {
            float c = ssc[r * KCNT + lane + 64 * j];
            if (c < v1) { v2 = v1; v1 = c; i1 = lane + 64 * j; }
            else        { v2 = fminf(v2, c); }
        }
#pragma unroll
        for (int off = 32; off; off >>= 1) {
            float w1 = __shfl_xor(v1, off, 64);
            int   j1 = __shfl_xor(i1, off, 64);
            float w2 = __shfl_xor(v2, off, 64);
            if (w1 < v1 || (w1 == v1 && j1 < i1)) { v2 = fminf(v1, w2); v1 = w1; i1 = j1; }
            else                                  { v2 = fminf(v2, w1); }
        }
        if (lane == 0) { sidx[r] = i1; sgap[r] = v2 - v1; }
    }
    __syncthreads();
    for (int fr = 0; fr < FB_ROWS; ++fr) {
        if (sgap[fr] < 0.02f) {
            double dotd = 0.0, k2d = 0.0;
            const float4* xrow = x4 + (size_t)(row0 + fr) * C4;
#pragma unroll 4
            for (int c4 = 0; c4 < C4; ++c4) {
                float4 xv = xrow[c4];
                float4 kv = ((const float4*)keys)[(size_t)t * C4 + c4];
                dotd += (double)kv.x * (double)xv.x; k2d += (double)kv.x * (double)kv.x;
                dotd += (double)kv.y * (double)xv.y; k2d += (double)kv.y * (double)kv.y;
                dotd += (double)kv.z * (double)xv.z; k2d += (double)kv.z * (double)kv.z;
                dotd += (double)kv.w * (double)xv.w; k2d += (double)kv.w * (double)kv.w;
            }
            double sd = k2d - 2.0 * dotd;
            int    si = t;
#pragma unroll
            for (int off = 32; off; off >>= 1) {
                double od = __shfl_xor(sd, off, 64);
                int    oi = __shfl_xor(si, off, 64);
                if (od < sd || (od == sd && oi < si)) { sd = od; si = oi; }
            }
            if ((t & 63) == 0) { dva[wave] = sd; dia[wave] = si; }
            __syncthreads();
            if (t == 0) {
                double b = dva[0]; int bi = dia[0];
#pragma unroll
                for (int ww = 1; ww < 4; ++ww)
                    if (dva[ww] < b || (dva[ww] == b && dia[ww] < bi)) { b = dva[ww]; bi = dia[ww]; }
                sidx[fr] = bi;
            }
            __syncthreads();
        }
    }
    const float4* v4p = (const float4*)values;
    float4* o4 = (float4*)out;
#pragma unroll
    for (int r = 0; r < FB_ROWS; ++r) {
        const int idx = sidx[r];
        o4[(size_t)(row0 + r) * C4 + t] = v4p[(size_t)idx * C4 + t];
    }
}

extern "C" void kernel_launch(void* const* d_in, const int* in_sizes, int n_in,
                              void* d_out, int out_size, void* d_ws, size_t ws_size,
                              hipStream_t stream) {
    const float* x      = (const float*)d_in[0];
    const float* keys   = (const float*)d_in[1];
    const float* values = (const float*)d_in[2];
    float* out = (float*)d_out;

    const int nrows = in_sizes[0] / C_IN;  // 16384
    const size_t need = 1048576u + 1024u;  // img + k2

    if (d_ws != nullptr && ws_size >= need && (nrows % MB) == 0) {
        unsigned short* img = (unsigned short*)d_ws;
        float* k2 = (float*)((char*)d_ws + 1048576);
        prep_img<<<KCNT, 256, 0, stream>>>(keys, img, k2);
        vq_pipe<<<nrows / MB, 256, 0, stream>>>(x, keys, img, k2, values, out);
    } else {
        codebook_fallback<<<nrows / FB_ROWS, 256, 0, stream>>>(x, keys, values, out);
    }
}